// Round 12
// baseline (127.204 us; speedup 1.0000x reference)
//
#include <hip/hip_runtime.h>

#define IN_DIM 256
#define OUT_DIM 128
#define LEAKY 0.01f
#define GEMM_BLOCKS 512
#define NSLICE 8

typedef __attribute__((ext_vector_type(8))) short bf16x8;
typedef __attribute__((ext_vector_type(4))) float f32x4;
typedef __attribute__((ext_vector_type(4))) unsigned u32x4;

// RNE f32->bf16 pack (2 at a time). No builtin on gfx950 -> inline asm.
__device__ inline unsigned cvtpk_bf16(float lo, float hi) {
  unsigned r;
  asm volatile("v_cvt_pk_bf16_f32 %0, %1, %2" : "=v"(r) : "v"(lo), "v"(hi));
  return r;
}

// unpack a u32 holding two bf16 (little-endian: low short = even col)
__device__ inline float blo(unsigned u) {
  union { unsigned x; float f; } c; c.x = u << 16; return c.f;
}
__device__ inline float bhi(unsigned u) {
  union { unsigned x; float f; } c; c.x = u & 0xFFFF0000u; return c.f;
}
__device__ inline float asf(unsigned u) {
  union { unsigned x; float f; } c; c.x = u; return c.f;
}

// LDS swizzle for a [rows][256bf16] tile, measured 0 bank conflicts (R4/R8):
// 16B unit u of row r lives at byte r*512 + ((u&16)<<4) + (((u&15)^(r&15))<<4)
__device__ inline int swz_byte(int r, int u) {
  return r * 512 + ((u & 16) << 4) + (((u & 15) ^ (r & 15)) << 4);
}

// ---------------------------------------------------------------------------
// Kernel 1 (fused, 3 block roles):
//  [0, GEMM_BLOCKS):       MFMA GEMM -> SLICE-MAJOR support [8][nrows][16]
//  [GEMM, GEMM+scan):      adjacent-difference scan -> row_starts
//  [GEMM+scan, +pack):     pack (col, valbits) interleaved into ev[]
// ---------------------------------------------------------------------------
__global__ __launch_bounds__(512, 4) void gemm_scan_pack(
    const float* __restrict__ feat, const float* __restrict__ w,
    const int* __restrict__ erows, const int* __restrict__ ecols,
    const float* __restrict__ evals, unsigned short* __restrict__ support,
    int* __restrict__ rs, unsigned* __restrict__ ev, int nrows, int nedges,
    int ntiles, int scan_blocks) {
  if (blockIdx.x >= GEMM_BLOCKS) {
    const int sb = blockIdx.x - GEMM_BLOCKS;
    if (sb < scan_blocks) {
      // ---- scan: rs[r] = lower_bound(erows, r), sentinel rs[nrows] ----
      const int i = sb * 512 + threadIdx.x;
      if (i >= nedges) return;
      const int cur  = erows[i];
      const int prev = (i == 0) ? -1 : erows[i - 1];
      for (int r = prev + 1; r <= cur; ++r) rs[r] = i;
      if (i == nedges - 1)
        for (int r = cur + 1; r <= nrows; ++r) rs[r] = nedges;
    } else {
      // ---- pack: ev[2i]=col(i), ev[2i+1]=bits(val(i)), 2 edges/thread ----
      const int p = (sb - scan_blocks) * 512 + threadIdx.x;  // pair index
      if (p * 2 + 1 >= nedges) {
        if (p * 2 < nedges) {
          ev[p * 4 + 0] = (unsigned)ecols[p * 2];
          ev[p * 4 + 1] = __float_as_uint(evals[p * 2]);
        }
        return;
      }
      const int2   c2 = *reinterpret_cast<const int2*>(&ecols[p * 2]);
      const float2 v2 = *reinterpret_cast<const float2*>(&evals[p * 2]);
      uint4 o;
      o.x = (unsigned)c2.x;
      o.y = __float_as_uint(v2.x);
      o.z = (unsigned)c2.y;
      o.w = __float_as_uint(v2.y);
      reinterpret_cast<uint4*>(ev)[p] = o;
    }
    return;
  }

  // ---- GEMM part ----
  __shared__ alignas(16) unsigned short wlds[128 * 256];  // 64 KB, swizzled
  char* wb = reinterpret_cast<char*>(wlds);

  const int t = threadIdx.x;
#pragma unroll
  for (int it = 0; it < 8; ++it) {
    const int g = it * 512 + t;  // unit index 0..4095
    const int r = g >> 5;
    const int u = g & 31;
    const float* src = w + r * IN_DIM + u * 8;
    const float4 a = *reinterpret_cast<const float4*>(src);
    const float4 b = *reinterpret_cast<const float4*>(src + 4);
    uint4 pk;
    pk.x = cvtpk_bf16(a.x, a.y);
    pk.y = cvtpk_bf16(a.z, a.w);
    pk.z = cvtpk_bf16(b.x, b.y);
    pk.w = cvtpk_bf16(b.z, b.w);
    *reinterpret_cast<uint4*>(wb + swz_byte(r, u)) = pk;
  }
  __syncthreads();

  const int wid  = t >> 6;
  const int lane = t & 63;
  const int lrow = lane & 15;
  const int hi   = lane >> 4;
  const size_t slice_stride = (size_t)nrows * 16;

  for (int tile = blockIdx.x; tile < ntiles; tile += GEMM_BLOCKS) {
    const int mrow = tile * 128 + wid * 16 + lrow;
    const int mr   = mrow < nrows ? mrow : nrows - 1;
    const float* fp = feat + mr * IN_DIM + hi * 8;

    f32x4 acc[8];
#pragma unroll
    for (int nt = 0; nt < 8; ++nt) acc[nt] = (f32x4){0.f, 0.f, 0.f, 0.f};

#pragma unroll
    for (int ks = 0; ks < 8; ++ks) {
      const float4 a = *reinterpret_cast<const float4*>(fp + ks * 32);
      const float4 b = *reinterpret_cast<const float4*>(fp + ks * 32 + 4);
      union { bf16x8 v; unsigned u[4]; } bf;
      bf.u[0] = cvtpk_bf16(a.x, a.y);
      bf.u[1] = cvtpk_bf16(a.z, a.w);
      bf.u[2] = cvtpk_bf16(b.x, b.y);
      bf.u[3] = cvtpk_bf16(b.z, b.w);
      const int u = ks * 4 + hi;
#pragma unroll
      for (int nt = 0; nt < 8; ++nt) {
        const bf16x8 af = *reinterpret_cast<const bf16x8*>(
            wb + swz_byte(nt * 16 + lrow, u));
        acc[nt] = __builtin_amdgcn_mfma_f32_16x16x32_bf16(af, bf.v, acc[nt],
                                                          0, 0, 0);
      }
    }

    if (mrow < nrows) {
      // slice-major: cols nt*16 + hi*4 + [0,4) -> slice nt, within-slice
      // offset hi*4; row-contig 32B per support row inside each slice.
#pragma unroll
      for (int nt = 0; nt < 8; ++nt) {
        f32x4 v = acc[nt];
        float a0 = v[0] > 0.f ? v[0] : LEAKY * v[0];
        float a1 = v[1] > 0.f ? v[1] : LEAKY * v[1];
        float a2 = v[2] > 0.f ? v[2] : LEAKY * v[2];
        float a3 = v[3] > 0.f ? v[3] : LEAKY * v[3];
        uint2 st;
        st.x = cvtpk_bf16(a0, a1);
        st.y = cvtpk_bf16(a2, a3);
        unsigned short* o =
            support + nt * slice_stride + (size_t)mrow * 16 + hi * 4;
        *reinterpret_cast<uint2*>(o) = st;
      }
    }
  }
}

// ---------------------------------------------------------------------------
// Kernel 2: out[r] = sum over edges (r,c,v) of v * support[c]
// XCD-pinned column slices: slice = blockIdx % 8 (round-robin dispatch pins
// slice s to XCD s), slice table = nrows*32B = 3.2 MB -> L2-RESIDENT, so
// gathers are L2 hits; HBM/L3 random misses drop to compulsory.
// Quarter-wave (16 lanes) = 1 row; lane (j=lq>>1, h=lq&1): edge slot j,
// 16B half h. Per 8-edge batch: ONE uint2 ev load + ONE 16B gather.
// Row end: __shfl_xor (2,4,8) tree reduce over j; lanes j==0 store the
// 16-col slice of out (2 x 16B NT stores, static reg indexing).
// ---------------------------------------------------------------------------
__global__ __launch_bounds__(256) void spmm_sliced(
    const int* __restrict__ rs, const uint2* __restrict__ ev,
    const unsigned short* __restrict__ support, float* __restrict__ out,
    int nrows) {
  const int t     = threadIdx.x;
  const int s     = blockIdx.x & (NSLICE - 1);  // slice -> XCD pin
  const int chunk = blockIdx.x >> 3;
  const int row   = chunk * 16 + (t >> 4);      // quarter-wave id 0..15
  const int lq    = t & 15;
  const int j     = lq >> 1;                    // edge slot 0..7
  const int h     = lq & 1;                     // 16B half of 32B slice row
  if (row >= nrows) return;

  const int es = rs[row];
  const int ee = rs[row + 1];
  const unsigned short* sbase = support + (size_t)s * nrows * 16 + h * 8;

  f32x4 a0 = {0.f, 0.f, 0.f, 0.f}, a1 = {0.f, 0.f, 0.f, 0.f};

  for (int base = es; base < ee; base += 8) {
    const int  idx = base + j;
    const bool ok  = idx < ee;
    const uint2 p  = ev[ok ? idx : ee - 1];
    const float v  = ok ? asf(p.y) : 0.f;
    const u32x4 u =
        *reinterpret_cast<const u32x4*>(sbase + (size_t)p.x * 16);
    a0[0] += v * blo(u[0]);
    a0[1] += v * bhi(u[0]);
    a0[2] += v * blo(u[1]);
    a0[3] += v * bhi(u[1]);
    a1[0] += v * blo(u[2]);
    a1[1] += v * bhi(u[2]);
    a1[2] += v * blo(u[3]);
    a1[3] += v * bhi(u[3]);
  }

  // reduce over edge slots j (lane bits 1,2,3)
#pragma unroll
  for (int m = 2; m <= 8; m <<= 1) {
#pragma unroll
    for (int k = 0; k < 4; ++k) {
      a0[k] += __shfl_xor(a0[k], m);
      a1[k] += __shfl_xor(a1[k], m);
    }
  }

  if (j == 0) {
    float* o = out + (size_t)row * OUT_DIM + s * 16 + h * 8;
    __builtin_nontemporal_store(a0, reinterpret_cast<f32x4*>(o));
    __builtin_nontemporal_store(a1, reinterpret_cast<f32x4*>(o + 4));
  }
}

// ---------------------------------------------------------------------------
extern "C" void kernel_launch(void* const* d_in, const int* in_sizes, int n_in,
                              void* d_out, int out_size, void* d_ws,
                              size_t ws_size, hipStream_t stream) {
  const float* features = (const float*)d_in[0];
  const float* weight   = (const float*)d_in[1];
  const int*   erows    = (const int*)d_in[2];
  const int*   ecols    = (const int*)d_in[3];
  const float* evals    = (const float*)d_in[4];
  float*       out      = (float*)d_out;

  const int nrows  = in_sizes[0] / IN_DIM;  // 100000
  const int nedges = in_sizes[2];           // 1600000

  // ws layout: support bf16 slice-major (25.6 MB) | row_starts (~400 KB) |
  //            ev packed (12.8 MB). Total ~38.8 MB.
  const size_t sup_bytes = (size_t)nrows * OUT_DIM * 2;
  const size_t rs_bytes  = (((size_t)(nrows + 1) * 4 + 15) / 16) * 16;
  unsigned short* support = (unsigned short*)d_ws;
  int*      rs = (int*)((char*)d_ws + sup_bytes);
  unsigned* ev = (unsigned*)((char*)d_ws + sup_bytes + rs_bytes);

  const int ntiles      = (nrows + 127) / 128;
  const int scan_blocks = (nedges + 511) / 512;
  const int pack_blocks = ((nedges / 2) + 511) / 512;

  gemm_scan_pack<<<GEMM_BLOCKS + scan_blocks + pack_blocks, 512, 0, stream>>>(
      features, weight, erows, ecols, evals, support, rs, ev, nrows, nedges,
      ntiles, scan_blocks);

  const int chunks = (nrows + 15) / 16;
  spmm_sliced<<<chunks * NSLICE, 256, 0, stream>>>(
      rs, reinterpret_cast<const uint2*>(ev), support, out, nrows);
}

// Round 13
// 93.511 us; speedup vs baseline: 1.3603x; 1.3603x over previous
//
#include <hip/hip_runtime.h>

#define IN_DIM 256
#define OUT_DIM 128
#define LEAKY 0.01f
#define GEMM_BLOCKS 391   // 782 tiles / 391 = exactly 2 tiles per block
#define SPMM_BLOCKS 2048  // 8 blocks/CU x 4 waves = full residency

typedef __attribute__((ext_vector_type(8))) short bf16x8;
typedef __attribute__((ext_vector_type(4))) float f32x4;
typedef __attribute__((ext_vector_type(4))) unsigned u32x4;

// RNE f32->bf16 pack (2 at a time). No builtin on gfx950 -> inline asm.
__device__ inline unsigned cvtpk_bf16(float lo, float hi) {
  unsigned r;
  asm volatile("v_cvt_pk_bf16_f32 %0, %1, %2" : "=v"(r) : "v"(lo), "v"(hi));
  return r;
}

// unpack a u32 holding two bf16 (little-endian: low short = even col)
__device__ inline float blo(unsigned u) {
  union { unsigned x; float f; } c; c.x = u << 16; return c.f;
}
__device__ inline float bhi(unsigned u) {
  union { unsigned x; float f; } c; c.x = u & 0xFFFF0000u; return c.f;
}

// LDS swizzle for a [rows][256bf16] tile, measured 0 bank conflicts (R4/R8):
// 16B unit u of row r lives at byte r*512 + ((u&16)<<4) + (((u&15)^(r&15))<<4)
__device__ inline int swz_byte(int r, int u) {
  return r * 512 + ((u & 16) << 4) + (((u & 15) ^ (r & 15)) << 4);
}

// ---------------------------------------------------------------------------
// Kernel 1 (fused): blocks < GEMM_BLOCKS run the MFMA GEMM (W cvt'd
// fp32->bf16 into swizzled LDS, features direct from global, each block
// exactly 2 tiles - balanced); blocks >= GEMM_BLOCKS run the adjacent-
// difference scan -> row_starts (co-scheduled on leftover wave slots).
// ---------------------------------------------------------------------------
__global__ __launch_bounds__(512, 4) void gemm_scan(
    const float* __restrict__ feat, const float* __restrict__ w,
    const int* __restrict__ erows, unsigned short* __restrict__ support,
    int* __restrict__ rs, int nrows, int nedges, int ntiles) {
  if (blockIdx.x >= GEMM_BLOCKS) {
    // ---- scan: rs[r] = lower_bound(erows, r), sentinel rs[nrows] ----
    const int i = (blockIdx.x - GEMM_BLOCKS) * 512 + threadIdx.x;
    if (i >= nedges) return;
    const int cur  = erows[i];
    const int prev = (i == 0) ? -1 : erows[i - 1];
    for (int r = prev + 1; r <= cur; ++r) rs[r] = i;
    if (i == nedges - 1)
      for (int r = cur + 1; r <= nrows; ++r) rs[r] = nedges;
    return;
  }

  // ---- GEMM part ----
  __shared__ alignas(16) unsigned short wlds[128 * 256];  // 64 KB, swizzled
  char* wb = reinterpret_cast<char*>(wlds);

  const int t = threadIdx.x;
  // stage W fp32 -> bf16 -> swizzled LDS (4096 16B units, 8 per thread)
#pragma unroll
  for (int it = 0; it < 8; ++it) {
    const int g = it * 512 + t;  // unit index 0..4095
    const int r = g >> 5;        // W row 0..127
    const int u = g & 31;        // 16B unit within row
    const float* src = w + r * IN_DIM + u * 8;
    const float4 a = *reinterpret_cast<const float4*>(src);
    const float4 b = *reinterpret_cast<const float4*>(src + 4);
    uint4 pk;
    pk.x = cvtpk_bf16(a.x, a.y);
    pk.y = cvtpk_bf16(a.z, a.w);
    pk.z = cvtpk_bf16(b.x, b.y);
    pk.w = cvtpk_bf16(b.z, b.w);
    *reinterpret_cast<uint4*>(wb + swz_byte(r, u)) = pk;
  }
  __syncthreads();

  const int wid  = t >> 6;
  const int lane = t & 63;
  const int lrow = lane & 15;
  const int hi   = lane >> 4;

  for (int tile = blockIdx.x; tile < ntiles; tile += GEMM_BLOCKS) {
    const int mrow = tile * 128 + wid * 16 + lrow;
    const int mr   = mrow < nrows ? mrow : nrows - 1;
    const float* fp = feat + mr * IN_DIM + hi * 8;

    f32x4 acc[8];
#pragma unroll
    for (int nt = 0; nt < 8; ++nt) acc[nt] = (f32x4){0.f, 0.f, 0.f, 0.f};

#pragma unroll
    for (int ks = 0; ks < 8; ++ks) {
      const float4 a = *reinterpret_cast<const float4*>(fp + ks * 32);
      const float4 b = *reinterpret_cast<const float4*>(fp + ks * 32 + 4);
      union { bf16x8 v; unsigned u[4]; } bf;
      bf.u[0] = cvtpk_bf16(a.x, a.y);
      bf.u[1] = cvtpk_bf16(a.z, a.w);
      bf.u[2] = cvtpk_bf16(b.x, b.y);
      bf.u[3] = cvtpk_bf16(b.z, b.w);
      const int u = ks * 4 + hi;
#pragma unroll
      for (int nt = 0; nt < 8; ++nt) {
        const bf16x8 af = *reinterpret_cast<const bf16x8*>(
            wb + swz_byte(nt * 16 + lrow, u));
        acc[nt] = __builtin_amdgcn_mfma_f32_16x16x32_bf16(af, bf.v, acc[nt],
                                                          0, 0, 0);
      }
    }

    if (mrow < nrows) {
      unsigned short* orow = support + mrow * OUT_DIM + hi * 4;
#pragma unroll
      for (int nt = 0; nt < 8; ++nt) {
        f32x4 v = acc[nt];
        float a0 = v[0] > 0.f ? v[0] : LEAKY * v[0];
        float a1 = v[1] > 0.f ? v[1] : LEAKY * v[1];
        float a2 = v[2] > 0.f ? v[2] : LEAKY * v[2];
        float a3 = v[3] > 0.f ? v[3] : LEAKY * v[3];
        uint2 st;
        st.x = cvtpk_bf16(a0, a1);
        st.y = cvtpk_bf16(a2, a3);
        *reinterpret_cast<uint2*>(orow + nt * 16) = st;
      }
    }
  }
}

// ---------------------------------------------------------------------------
// Kernel 2: out[r] = sum over edges (r,c,v) of v * support_bf16[c]
// R10's proven best inner loop (65.6 us): wave = 4 rows x 16 lanes, lane
// owns 8 cols, 16B u32x4 gathers, predicated unroll-8, NT out stores.
// NEW: persistent grid-stride outer loop (2048 blocks = 32 waves/CU full
// residency) instead of 6250 short-lived blocks (occupancy was 34%).
// ---------------------------------------------------------------------------
__global__ __launch_bounds__(256) void spmm_bf16(
    const int* __restrict__ rs, const int* __restrict__ ecols,
    const float* __restrict__ evals, const unsigned short* __restrict__ support,
    float* __restrict__ out, int nrows, int nchunks) {
  const int t    = threadIdx.x;
  const int lane = t & 15;  // 16 lanes per row
  const int rloc = t >> 4;  // row-within-chunk 0..15

  const unsigned short* srow = support + lane * 8;

  for (int chunk = blockIdx.x; chunk < nchunks; chunk += SPMM_BLOCKS) {
    const int row = chunk * 16 + rloc;
    if (row >= nrows) continue;

    const int s = rs[row];
    const int e = rs[row + 1];

    f32x4 accA[4], accB[4];
#pragma unroll
    for (int j = 0; j < 4; ++j) {
      accA[j] = (f32x4){0.f, 0.f, 0.f, 0.f};
      accB[j] = (f32x4){0.f, 0.f, 0.f, 0.f};
    }

    for (int i = s; i < e; i += 8) {
      int   ii[8];
      float vv[8];
#pragma unroll
      for (int j = 0; j < 8; ++j) {
        const int  idx = i + j;
        const bool ok  = idx < e;
        ii[j] = ok ? idx : e - 1;
        vv[j] = ok ? evals[ii[j]] : 0.f;
      }
#pragma unroll
      for (int j = 0; j < 8; ++j) {
        const int c = ecols[ii[j]];
        const u32x4 u =
            *reinterpret_cast<const u32x4*>(srow + (size_t)c * OUT_DIM);
        const int   k = j & 3;
        const float v = vv[j];
        accA[k][0] += v * blo(u[0]);
        accA[k][1] += v * bhi(u[0]);
        accA[k][2] += v * blo(u[1]);
        accA[k][3] += v * bhi(u[1]);
        accB[k][0] += v * blo(u[2]);
        accB[k][1] += v * bhi(u[2]);
        accB[k][2] += v * blo(u[3]);
        accB[k][3] += v * bhi(u[3]);
      }
    }

#pragma unroll
    for (int j = 1; j < 4; ++j) {
      accA[0] += accA[j];
      accB[0] += accB[j];
    }
    float* orow = out + (size_t)row * OUT_DIM + lane * 8;
    __builtin_nontemporal_store(accA[0], reinterpret_cast<f32x4*>(orow));
    __builtin_nontemporal_store(accB[0], reinterpret_cast<f32x4*>(orow + 4));
  }
}

// ---------------------------------------------------------------------------
extern "C" void kernel_launch(void* const* d_in, const int* in_sizes, int n_in,
                              void* d_out, int out_size, void* d_ws,
                              size_t ws_size, hipStream_t stream) {
  const float* features = (const float*)d_in[0];
  const float* weight   = (const float*)d_in[1];
  const int*   erows    = (const int*)d_in[2];
  const int*   ecols    = (const int*)d_in[3];
  const float* evals    = (const float*)d_in[4];
  float*       out      = (float*)d_out;

  const int nrows  = in_sizes[0] / IN_DIM;  // 100000
  const int nedges = in_sizes[2];           // 1600000

  // ws layout: support bf16 row-major (25.6 MB) | row_starts (400 KB)
  unsigned short* support = (unsigned short*)d_ws;
  int* rs = (int*)((char*)d_ws + (size_t)nrows * OUT_DIM * 2);

  const int ntiles      = (nrows + 127) / 128;  // 782 = 2 * GEMM_BLOCKS
  const int scan_blocks = (nedges + 511) / 512;
  const int nchunks     = (nrows + 15) / 16;

  gemm_scan<<<GEMM_BLOCKS + scan_blocks, 512, 0, stream>>>(
      features, weight, erows, support, rs, nrows, nedges, ntiles);
  spmm_bf16<<<SPMM_BLOCKS, 256, 0, stream>>>(rs, ecols, evals, support, out,
                                             nrows, nchunks);
}